// Round 19
// baseline (224.123 us; speedup 1.0000x reference)
//
#include <hip/hip_runtime.h>
#include <hip/hip_bf16.h>

typedef __attribute__((ext_vector_type(8))) short bf16x8;
typedef __attribute__((ext_vector_type(4))) float f32x4;

#define HWSZ 4096
#define NPIX 16384

__device__ inline float b2f(short s) {
  return __uint_as_float(((unsigned)(unsigned short)s) << 16);
}
__device__ inline short f2b(float f) {
  __hip_bfloat16 h = __float2bfloat16(f);
  return *(short*)&h;
}
__device__ inline void gl16(const short* g, short* l) {
  __builtin_amdgcn_global_load_lds(
      (const __attribute__((address_space(1))) unsigned int*)g,
      (__attribute__((address_space(3))) unsigned int*)l, 16, 0, 0);
}
template<int N> __device__ __forceinline__ void vmwait() {
  if constexpr (N == 0)      asm volatile("s_waitcnt vmcnt(0)" ::: "memory");
  else if constexpr (N == 3) asm volatile("s_waitcnt vmcnt(3)" ::: "memory");
  else if constexpr (N == 6) asm volatile("s_waitcnt vmcnt(6)" ::: "memory");
  else                       asm volatile("s_waitcnt vmcnt(4)" ::: "memory");
}
// GELU exact-erf via Abramowitz-Stegun 7.1.26 (|abs err| <= 1.5e-7)
__device__ inline float gelu_f(float x) {
  float ax = fabsf(x) * 0.70710678118654752f;
  float t = 1.f / (1.f + 0.3275911f * ax);
  float y = t * (0.254829592f + t * (-0.284496736f + t * (1.421413741f +
            t * (-1.453152027f + t * 1.061405429f))));
  float erfv = 1.f - y * __expf(-ax * ax);
  erfv = copysignf(erfv, x);
  return 0.5f * x * (1.f + erfv);
}

// ---------------- weight fp32 -> bf16 conversion ----------------
__global__ __launch_bounds__(256) void convert_k(
    const float* __restrict__ qw, const float* __restrict__ kw,
    const float* __restrict__ vw, const float* __restrict__ pw,
    const float* __restrict__ f1, const float* __restrict__ f2,
    __hip_bfloat16* __restrict__ out)
{
  int idx = blockIdx.x * 256 + threadIdx.x;
  if (idx >= 2 * 786432) return;
  int bi = idx / 786432;
  int r  = idx - bi * 786432;
  float v;
  if      (r <  65536) v = qw[bi*65536 + r];
  else if (r < 131072) v = kw[bi*65536 + r - 65536];
  else if (r < 196608) v = vw[bi*65536 + r - 131072];
  else if (r < 262144) v = pw[bi*65536 + r - 196608];
  else if (r < 524288) v = f1[bi*262144 + r - 262144];
  else                 v = f2[bi*262144 + r - 524288];
  out[idx] = __float2bfloat16(v);
}

// ---------------- fused prep: both LN1 variants + raw diff(bf16), BCHW -> (pix, ch) ----------------
__global__ __launch_bounds__(256) void prep2_k(
    const float* __restrict__ x,     // (2,4,256,64,64)
    const float* __restrict__ nw, const float* __restrict__ nb,
    __hip_bfloat16* __restrict__ ln1a,
    __hip_bfloat16* __restrict__ ln1b,
    __hip_bfloat16* __restrict__ diff,   // av*vi+ai*ir (raw, bf16)
    float av, float ai, float bv, float bb)
{
  __shared__ float t1[16][257], t2[16][257];
  __shared__ float red[4][16][16];
  __shared__ float mu1[16], rs1[16], mu2[16], rs2[16];
  int t = threadIdx.x;
  int pix0 = blockIdx.x * 16;
  int b = pix0 >> 12, hw0 = pix0 & 4095;
  const float* vi = x + (size_t)b * 256 * HWSZ;
  const float* ir = x + (size_t)(4 + b) * 256 * HWSZ;

  for (int it = 0; it < 16; ++it) {
    int idx = it * 256 + t;
    int p = idx & 15, c = idx >> 4;
    size_t off = (size_t)c * HWSZ + hw0 + p;
    float a = vi[off], bb2 = ir[off];
    t1[p][c] = av * a + ai * bb2;
    t2[p][c] = bv * a + bb * bb2;
  }
  __syncthreads();
  {
    int p = t & 15, q = t >> 4;
    float s1 = 0, ss1 = 0, s2 = 0, ss2 = 0;
    for (int i = 0; i < 16; ++i) {
      float v = t1[p][q*16 + i]; s1 += v; ss1 += v*v;
      float u = t2[p][q*16 + i]; s2 += u; ss2 += u*u;
    }
    red[0][p][q] = s1; red[1][p][q] = ss1; red[2][p][q] = s2; red[3][p][q] = ss2;
  }
  __syncthreads();
  if (t < 32) {
    int p = t & 15, which = t >> 4;
    float s = 0, ss = 0;
    for (int q = 0; q < 16; ++q) { s += red[which*2][p][q]; ss += red[which*2+1][p][q]; }
    float mu = s * (1.f/256.f);
    float var = ss * (1.f/256.f) - mu*mu;
    float rs = rsqrtf(var + 1e-5f);
    if (which == 0) { mu1[p] = mu; rs1[p] = rs; }
    else            { mu2[p] = mu; rs2[p] = rs; }
  }
  __syncthreads();
  for (int it = 0; it < 16; ++it) {
    float v1 = t1[it][t], v2 = t2[it][t];
    size_t o = (size_t)(pix0 + it) * 256 + t;
    ln1a[o] = __float2bfloat16((v1 - mu1[it]) * rs1[it] * nw[t] + nb[t]);
    ln1b[o] = __float2bfloat16((v2 - mu2[it]) * rs2[it] * nw[t] + nb[t]);
    diff[o] = __float2bfloat16(v1);
  }
}

// ---------------- 256-thread GEMM core (round-11 proven; used for proj) ----------------
template<int EPI, int BN>
__device__ __forceinline__ void gemm_core(
    const short* __restrict__ A, const short* __restrict__ W,
    void* __restrict__ outp, const float* __restrict__ bias,
    const short* __restrict__ res, int K, int ldc, int m0, int n0)
{
  constexpr int NI = (BN == 128) ? 4 : 2;
  __shared__ __align__(16) short As[2][64 * 32];
  __shared__ __align__(16) short Bs[2][BN * 32];
  int tid = threadIdx.x;
  int l = tid & 63, wv = tid >> 6;
  int wm = wv >> 1, wn = wv & 1;
  int lr = l & 15, lq = l >> 4;

  int srow = tid >> 2;
  int sch = (tid & 3) ^ ((srow >> 1) & 3);
  const short* gA = A + (size_t)(m0 + srow) * K + sch * 8;
  const short* gB = W + (size_t)(n0 + srow) * K + sch * 8;
  const short* gB1 = (BN == 128) ? (W + (size_t)(n0 + srow + 64) * K + sch * 8) : nullptr;

  f32x4 acc[2][NI];
  #pragma unroll
  for (int mi = 0; mi < 2; ++mi)
    #pragma unroll
    for (int ni = 0; ni < NI; ++ni) acc[mi][ni] = (f32x4){0.f, 0.f, 0.f, 0.f};

  gl16(gA, &As[0][0] + tid * 8);
  gl16(gB, &Bs[0][0] + tid * 8);
  if constexpr (BN == 128) gl16(gB1, &Bs[0][0] + 2048 + tid * 8);
  __syncthreads();

  int cur = 0;
  int rowa0 = wm * 32 + lr;
  int rowb0 = wn * (BN / 2) + lr;
  for (int k0 = 0; k0 < K; k0 += 32) {
    int kn = k0 + 32;
    if (kn < K) {
      gl16(gA + kn, &As[cur ^ 1][0] + tid * 8);
      gl16(gB + kn, &Bs[cur ^ 1][0] + tid * 8);
      if constexpr (BN == 128) gl16(gB1 + kn, &Bs[cur ^ 1][0] + 2048 + tid * 8);
    }
    bf16x8 af[2], bfr[NI];
    #pragma unroll
    for (int mi = 0; mi < 2; ++mi) {
      int row = rowa0 + mi * 16;
      int kc = lq ^ ((row >> 1) & 3);
      af[mi] = *(const bf16x8*)(&As[cur][0] + row * 32 + kc * 8);
    }
    #pragma unroll
    for (int ni = 0; ni < NI; ++ni) {
      int row = rowb0 + ni * 16;
      int kc = lq ^ ((row >> 1) & 3);
      bfr[ni] = *(const bf16x8*)(&Bs[cur][0] + row * 32 + kc * 8);
    }
    #pragma unroll
    for (int mi = 0; mi < 2; ++mi)
      #pragma unroll
      for (int ni = 0; ni < NI; ++ni)
        acc[mi][ni] = __builtin_amdgcn_mfma_f32_16x16x32_bf16(af[mi], bfr[ni], acc[mi][ni], 0, 0, 0);
    __syncthreads();
    cur ^= 1;
  }

  #pragma unroll
  for (int mi = 0; mi < 2; ++mi)
  #pragma unroll
  for (int ni = 0; ni < NI; ++ni) {
    int row0 = m0 + wm * 32 + mi * 16 + lq * 4;
    int col = n0 + wn * (BN / 2) + ni * 16 + lr;
    #pragma unroll
    for (int r = 0; r < 4; ++r) {
      int row = row0 + r;
      float v = acc[mi][ni][r];
      if (EPI == 0) {
        ((short*)outp)[(size_t)row * ldc + col] = f2b(v);
      } else {
        v += bias[col] + b2f(res[(size_t)row * 256 + col]);
        ((short*)outp)[(size_t)row * 256 + col] = f2b(v);
      }
    }
  }
}

template<int EPI, int BN>
__global__ __launch_bounds__(256) void gemm6_k(
    const short* __restrict__ A, const short* __restrict__ W,
    void* __restrict__ outp, const float* __restrict__ bias,
    const short* __restrict__ res, int K, int ldc)
{
  gemm_core<EPI, BN>(A, W, outp, bias, res, K, ldc, blockIdx.x * 64, blockIdx.y * BN);
}

// ---------------- 512-thread GEMM core: 128x128 tile, 8 waves (2m x 4n), wave 64x32 ----------------
// Proven (fc1 r16, qkv r18). Needs grid >= 3 blocks/CU to pay (round-17 lesson).
template<int EPI>
__device__ __forceinline__ void g512_core(
    const short* __restrict__ A, const short* __restrict__ W,
    void* __restrict__ outp, const float* __restrict__ bias,
    int K, int ldc, int m0, int n0)
{
  __shared__ __align__(16) short As[2][128 * 32];   // 8 KB each
  __shared__ __align__(16) short Bs[2][128 * 32];
  int tid = threadIdx.x;               // 0..511
  int l = tid & 63, wv = tid >> 6;     // 8 waves
  int wm = wv >> 2, wn = wv & 3;       // 2 x 4
  int lr = l & 15, lq = l >> 4;

  int srow = tid >> 2;
  int sch = (tid & 3) ^ ((srow >> 1) & 3);
  const short* gA = A + (size_t)(m0 + srow) * K + sch * 8;
  const short* gB = W + (size_t)(n0 + srow) * K + sch * 8;

  f32x4 acc[4][2];
  #pragma unroll
  for (int mi = 0; mi < 4; ++mi)
    #pragma unroll
    for (int ni = 0; ni < 2; ++ni) acc[mi][ni] = (f32x4){0.f, 0.f, 0.f, 0.f};

  gl16(gA, &As[0][0] + tid * 8);
  gl16(gB, &Bs[0][0] + tid * 8);
  __syncthreads();

  int cur = 0;
  int rowa0 = wm * 64 + lr;
  int rowb0 = wn * 32 + lr;
  for (int k0 = 0; k0 < K; k0 += 32) {
    int kn = k0 + 32;
    if (kn < K) {
      gl16(gA + kn, &As[cur ^ 1][0] + tid * 8);
      gl16(gB + kn, &Bs[cur ^ 1][0] + tid * 8);
    }
    bf16x8 af[4], bfr[2];
    #pragma unroll
    for (int mi = 0; mi < 4; ++mi) {
      int row = rowa0 + mi * 16;
      int kc = lq ^ ((row >> 1) & 3);
      af[mi] = *(const bf16x8*)(&As[cur][0] + row * 32 + kc * 8);
    }
    #pragma unroll
    for (int ni = 0; ni < 2; ++ni) {
      int row = rowb0 + ni * 16;
      int kc = lq ^ ((row >> 1) & 3);
      bfr[ni] = *(const bf16x8*)(&Bs[cur][0] + row * 32 + kc * 8);
    }
    #pragma unroll
    for (int mi = 0; mi < 4; ++mi)
      #pragma unroll
      for (int ni = 0; ni < 2; ++ni)
        acc[mi][ni] = __builtin_amdgcn_mfma_f32_16x16x32_bf16(af[mi], bfr[ni], acc[mi][ni], 0, 0, 0);
    __syncthreads();
    cur ^= 1;
  }

  #pragma unroll
  for (int mi = 0; mi < 4; ++mi)
  #pragma unroll
  for (int ni = 0; ni < 2; ++ni) {
    #pragma unroll
    for (int r = 0; r < 4; ++r) {
      int row = m0 + wm * 64 + mi * 16 + lq * 4 + r;
      int col = n0 + wn * 32 + ni * 16 + lr;
      float v = acc[mi][ni][r];
      if (EPI == 2) v = gelu_f(v + bias[col]);
      ((short*)outp)[(size_t)row * ldc + col] = f2b(v);
    }
  }
}

template<int EPI>
__global__ __launch_bounds__(512) void g512_k(
    const short* __restrict__ A, const short* __restrict__ W,
    void* __restrict__ outp, const float* __restrict__ bias,
    int K, int ldc)
{
  g512_core<EPI>(A, W, outp, bias, K, ldc, blockIdx.x * 128, blockIdx.y * 128);
}

// Q + KV in one 512-thread dispatch: y<2 -> Q (N=256), y>=2 -> KV (N=512); 768 blocks = 3/CU
__global__ __launch_bounds__(512) void qkv512_k(
    const short* __restrict__ ln1a, const short* __restrict__ ln1b,
    const short* __restrict__ wq, const short* __restrict__ wkv,
    short* __restrict__ qbuf, short* __restrict__ kv)
{
  bool isQ = blockIdx.y < 2;
  const short* A = isQ ? ln1a : ln1b;
  const short* W = isQ ? wq : wkv;
  void* outp = isQ ? (void*)qbuf : (void*)kv;
  int ldc = isQ ? 256 : 512;
  int n0 = (isQ ? blockIdx.y : (blockIdx.y - 2)) * 128;
  g512_core<0>(A, W, outp, nullptr, 256, ldc, blockIdx.x * 128, n0);
}

// ---------------- fc2 big-M ring GEMM: BM=128 x BN=64, 256 thr, ring-4 counted-vmcnt ----------------
// 4 waves 2m x 2n, wave 64x32 (acc 32 AGPR). IPT=3 gl16/thread/tile (As 2, Bs 1);
// steady s_waitcnt vmcnt(6) keeps 2 tiles in flight across each barrier. LDS 48 KB.
// Halves barrier events per output vs BM=64; grid (128,4) = 512 blocks = 2/CU.
// EPI: fp32 BCHW float4 = acc + bias[col] + b2f(res[row*256+col]).
__global__ __launch_bounds__(256) void gemm10_k(
    const short* __restrict__ A, const short* __restrict__ W,
    float* __restrict__ outp, const float* __restrict__ bias,
    const short* __restrict__ res, int K, int ldc)
{
  __shared__ __align__(16) short As[4][128 * 32];   // 8 KB each
  __shared__ __align__(16) short Bs[4][64 * 32];    // 4 KB each
  int tid = threadIdx.x;
  int l = tid & 63, wv = tid >> 6;
  int wm = wv >> 1, wn = wv & 1;
  int m0 = blockIdx.x * 128;
  int n0 = blockIdx.y * 64;
  int lr = l & 15, lq = l >> 4;

  // staging: As slots {tid, 256+tid} (rows 0-63, 64-127), Bs slot tid; src-side swizzle
  int srow0 = tid >> 2;
  int sch0 = (tid & 3) ^ ((srow0 >> 1) & 3);
  const short* gA0 = A + (size_t)(m0 + srow0) * K + sch0 * 8;
  const short* gA1 = A + (size_t)(m0 + 64 + srow0) * K + sch0 * 8;
  const short* gB  = W + (size_t)(n0 + srow0) * K + sch0 * 8;

  f32x4 acc[4][2];
  #pragma unroll
  for (int mi = 0; mi < 4; ++mi)
    #pragma unroll
    for (int ni = 0; ni < 2; ++ni) acc[mi][ni] = (f32x4){0.f, 0.f, 0.f, 0.f};

  int T = K >> 5;
  #pragma unroll
  for (int t0 = 0; t0 < 2; ++t0) {
    gl16(gA0 + t0 * 32, &As[t0][0] + tid * 8);
    gl16(gA1 + t0 * 32, &As[t0][0] + 2048 + tid * 8);
    gl16(gB  + t0 * 32, &Bs[t0][0] + tid * 8);
  }

  int rowa0 = wm * 64 + lr;
  int rowb0 = wn * 32 + lr;
  for (int t = 0; t < T; ++t) {
    if (t + 2 < T) {
      int b = (t + 2) & 3;
      gl16(gA0 + (t + 2) * 32, &As[b][0] + tid * 8);
      gl16(gA1 + (t + 2) * 32, &As[b][0] + 2048 + tid * 8);
      gl16(gB  + (t + 2) * 32, &Bs[b][0] + tid * 8);
    }
    if (t < T - 2)       vmwait<6>();
    else if (t == T - 2) vmwait<3>();
    else                 vmwait<0>();
    __builtin_amdgcn_s_barrier();

    int cb = t & 3;
    bf16x8 af[4], bfr[2];
    #pragma unroll
    for (int mi = 0; mi < 4; ++mi) {
      int row = rowa0 + mi * 16;
      int kc = lq ^ ((row >> 1) & 3);
      af[mi] = *(const bf16x8*)(&As[cb][0] + row * 32 + kc * 8);
    }
    #pragma unroll
    for (int ni = 0; ni < 2; ++ni) {
      int row = rowb0 + ni * 16;
      int kc = lq ^ ((row >> 1) & 3);
      bfr[ni] = *(const bf16x8*)(&Bs[cb][0] + row * 32 + kc * 8);
    }
    #pragma unroll
    for (int mi = 0; mi < 4; ++mi)
      #pragma unroll
      for (int ni = 0; ni < 2; ++ni)
        acc[mi][ni] = __builtin_amdgcn_mfma_f32_16x16x32_bf16(af[mi], bfr[ni], acc[mi][ni], 0, 0, 0);
  }

  #pragma unroll
  for (int mi = 0; mi < 4; ++mi)
  #pragma unroll
  for (int ni = 0; ni < 2; ++ni) {
    int row0 = m0 + wm * 64 + mi * 16 + lq * 4;
    int col = n0 + wn * 32 + ni * 16 + lr;
    float bc = bias[col];
    float4 o;
    #pragma unroll
    for (int r = 0; r < 4; ++r)
      ((float*)&o)[r] = acc[mi][ni][r] + bc + b2f(res[(size_t)(row0 + r) * 256 + col]);
    int b = row0 >> 12, hw = row0 & 4095;
    *(float4*)(outp + (size_t)(b * 256 + col) * HWSZ + hw) = o;
  }
}

// ---------------- dilated local attention: one thread per (pixel, head) ----------------
__global__ __launch_bounds__(256) void attn2_k(
    const __hip_bfloat16* __restrict__ Q,
    const __hip_bfloat16* __restrict__ KV,
    __hip_bfloat16* __restrict__ out)
{
  int gid = blockIdx.x * 256 + threadIdx.x;
  int pix = gid >> 3, head = gid & 7;
  int dil = (head >> 1) + 1;
  int y = (pix >> 6) & 63, xc = pix & 63;
  int base = pix & ~4095;
  const short* q8 = (const short*)Q + (size_t)pix * 256 + head * 32;
  float qf[32];
  #pragma unroll
  for (int j = 0; j < 4; ++j) {
    bf16x8 v = *(const bf16x8*)(q8 + j * 8);
    #pragma unroll
    for (int e = 0; e < 8; ++e) qf[j*8 + e] = b2f(v[e]);
  }
  float lg[9];
  int npx[9];
  #pragma unroll
  for (int t = 0; t < 9; ++t) {
    int ny = y + (t / 3 - 1) * dil;
    int nx = xc + (t % 3 - 1) * dil;
    bool ok = ((unsigned)ny < 64u) && ((unsigned)nx < 64u);
    npx[t] = ok ? (base | (ny * 64 + nx)) : -1;
    float d = 0.f;
    if (ok) {
      const short* k8 = (const short*)KV + (size_t)npx[t] * 512 + head * 32;
      #pragma unroll
      for (int j = 0; j < 4; ++j) {
        bf16x8 v = *(const bf16x8*)(k8 + j * 8);
        #pragma unroll
        for (int e = 0; e < 8; ++e) d += qf[j*8 + e] * b2f(v[e]);
      }
    }
    lg[t] = d * 0.17677669529663687f;   // 32^-0.5
  }
  float m = lg[0];
  #pragma unroll
  for (int t = 1; t < 9; ++t) m = fmaxf(m, lg[t]);
  float w[9], den = 0.f;
  #pragma unroll
  for (int t = 0; t < 9; ++t) { w[t] = expf(lg[t] - m); den += w[t]; }
  float inv = 1.f / den;
  float acc[32];
  #pragma unroll
  for (int j = 0; j < 32; ++j) acc[j] = 0.f;
  #pragma unroll
  for (int t = 0; t < 9; ++t) {
    if (npx[t] >= 0) {
      const short* v8 = (const short*)KV + (size_t)npx[t] * 512 + 256 + head * 32;
      float wt = w[t];
      #pragma unroll
      for (int j = 0; j < 4; ++j) {
        bf16x8 v = *(const bf16x8*)(v8 + j * 8);
        #pragma unroll
        for (int e = 0; e < 8; ++e) acc[j*8 + e] += wt * b2f(v[e]);
      }
    }
  }
  short* op = (short*)out + (size_t)pix * 256 + head * 32;
  #pragma unroll
  for (int j = 0; j < 4; ++j) {
    bf16x8 o;
    #pragma unroll
    for (int e = 0; e < 8; ++e) o[e] = f2b(acc[j*8 + e] * inv);
    *(bf16x8*)(op + j * 8) = o;
  }
}

// ---------------- LN2: bf16 (pix,ch) -> bf16 (pix,ch) ----------------
__global__ __launch_bounds__(256) void ln2b_k(
    const __hip_bfloat16* __restrict__ xm, const float* __restrict__ w2,
    const float* __restrict__ b2, __hip_bfloat16* __restrict__ h)
{
  int pix = blockIdx.x * 4 + (threadIdx.x >> 6);
  int l = threadIdx.x & 63;
  const short* p = (const short*)xm + (size_t)pix * 256 + l * 4;
  short4 sv = *(const short4*)p;
  float vv[4] = {b2f(sv.x), b2f(sv.y), b2f(sv.z), b2f(sv.w)};
  float s = vv[0] + vv[1] + vv[2] + vv[3];
  float ss = vv[0]*vv[0] + vv[1]*vv[1] + vv[2]*vv[2] + vv[3]*vv[3];
  #pragma unroll
  for (int off = 32; off; off >>= 1) { s += __shfl_xor(s, off); ss += __shfl_xor(ss, off); }
  float mu = s * (1.f/256.f);
  float rstd = rsqrtf(ss * (1.f/256.f) - mu*mu + 1e-5f);
  #pragma unroll
  for (int j = 0; j < 4; ++j) {
    int c = l * 4 + j;
    h[(size_t)pix * 256 + c] = __float2bfloat16((vv[j] - mu) * rstd * w2[c] + b2[c]);
  }
}

extern "C" void kernel_launch(void* const* d_in, const int* in_sizes, int n_in,
                              void* d_out, int out_size, void* d_ws, size_t ws_size,
                              hipStream_t stream)
{
  const float* x   = (const float*)d_in[0];
  const float* n1w = (const float*)d_in[1];
  const float* n1b = (const float*)d_in[2];
  const float* qw  = (const float*)d_in[3];
  const float* kw  = (const float*)d_in[4];
  const float* vw  = (const float*)d_in[5];
  const float* pw  = (const float*)d_in[6];
  const float* pb  = (const float*)d_in[7];
  const float* n2w = (const float*)d_in[8];
  const float* n2b = (const float*)d_in[9];
  const float* f1w = (const float*)d_in[10];
  const float* f1b = (const float*)d_in[11];
  const float* f2w = (const float*)d_in[12];
  const float* f2b = (const float*)d_in[13];
  float* outp = (float*)d_out;
  char* ws = (char*)d_ws;

  const size_t MB = 1024 * 1024;
  // Workspace high-water 51 MB (proven safe, same layout as rounds 6-18):
  //   [0,3)   wbf (whole session)
  //   [3,11)  ln1a -> attnb -> h(low)
  //   [11,19) ln1b -> h
  //   [19,27) diff bf16 -> h
  //   [27,35) qbuf -> h(high)
  //   [3,35)  h 32MB (fc1 out; all above dead by then)
  //   [35,51) kv -> xmid bf16 [35,43) + hb [43,51)
  __hip_bfloat16* wbf   = (__hip_bfloat16*)(ws);
  __hip_bfloat16* ln1a  = (__hip_bfloat16*)(ws + 3*MB);
  __hip_bfloat16* attnb = (__hip_bfloat16*)(ws + 3*MB);
  __hip_bfloat16* h     = (__hip_bfloat16*)(ws + 3*MB);
  __hip_bfloat16* ln1b  = (__hip_bfloat16*)(ws + 11*MB);
  __hip_bfloat16* diff  = (__hip_bfloat16*)(ws + 19*MB);
  __hip_bfloat16* qbuf  = (__hip_bfloat16*)(ws + 27*MB);
  __hip_bfloat16* kv    = (__hip_bfloat16*)(ws + 35*MB);
  __hip_bfloat16* xmid  = (__hip_bfloat16*)(ws + 35*MB);
  __hip_bfloat16* hb    = (__hip_bfloat16*)(ws + 43*MB);

  convert_k<<<6144, 256, 0, stream>>>(qw, kw, vw, pw, f1w, f2w, wbf);

  for (int bi = 0; bi < 2; ++bi) {
    const short* wq  = (const short*)(wbf + (size_t)bi * 786432);
    const short* wkv = wq + 65536;           // kw rows then vw rows (512 x 256)
    const short* wp  = wq + 196608;
    const short* w1  = wq + 262144;
    const short* w2  = wq + 524288;
    float av = (bi == 0) ? 1.f : -1.f, ai = (bi == 0) ? -1.f : 1.f;
    float bv = (bi == 0) ? 0.f : 1.f,  bb = (bi == 0) ? 1.f : 0.f;

    prep2_k<<<1024, 256, 0, stream>>>(x, n1w + bi*256, n1b + bi*256, ln1a, ln1b, diff, av, ai, bv, bb);

    // Q (y 0-1) + KV (y 2-5) in one 512-thread dispatch, K=256 (768 blocks = 3/CU)
    qkv512_k<<<dim3(128, 6), 512, 0, stream>>>(
        (const short*)ln1a, (const short*)ln1b, wq, wkv, (short*)qbuf, (short*)kv);

    attn2_k<<<512, 256, 0, stream>>>(qbuf, kv, attnb);

    // proj: N=256, K=256, +bias +residual(diff) -> xmid bf16 (256-thr, round-16 config)
    gemm6_k<1, 64><<<dim3(256, 4), 256, 0, stream>>>(
        (const short*)attnb, wp, xmid, pb + bi*256, (const short*)diff, 256, 256);
    ln2b_k<<<4096, 256, 0, stream>>>(xmid, n2w + bi*256, n2b + bi*256, hb);

    // fc1: N=1024, K=256, gelu -> h (512-thr, round-16 proven)
    g512_k<2><<<dim3(128, 8), 512, 0, stream>>>(
        (const short*)hb, w1, (void*)h, f1b + bi*1024, 256, 1024);
    // fc2: N=256, K=1024 -> big-M ring (BM=128, vmcnt(6), 2 tiles in flight), BCHW fp32 out
    gemm10_k<<<dim3(128, 4), 256, 0, stream>>>(
        (const short*)h, w2, outp + (size_t)bi * 4194304, f2b + bi*256, (const short*)xmid, 1024, 256);
  }
}

// Round 20
// 223.993 us; speedup vs baseline: 1.0006x; 1.0006x over previous
//
#include <hip/hip_runtime.h>
#include <hip/hip_bf16.h>

typedef __attribute__((ext_vector_type(8))) short bf16x8;
typedef __attribute__((ext_vector_type(4))) float f32x4;

#define HWSZ 4096
#define NPIX 16384

__device__ inline float b2f(short s) {
  return __uint_as_float(((unsigned)(unsigned short)s) << 16);
}
__device__ inline short f2b(float f) {
  __hip_bfloat16 h = __float2bfloat16(f);
  return *(short*)&h;
}
__device__ inline void gl16(const short* g, short* l) {
  __builtin_amdgcn_global_load_lds(
      (const __attribute__((address_space(1))) unsigned int*)g,
      (__attribute__((address_space(3))) unsigned int*)l, 16, 0, 0);
}
template<int N> __device__ __forceinline__ void vmwait() {
  if constexpr (N == 0)      asm volatile("s_waitcnt vmcnt(0)" ::: "memory");
  else if constexpr (N == 2) asm volatile("s_waitcnt vmcnt(2)" ::: "memory");
  else                       asm volatile("s_waitcnt vmcnt(4)" ::: "memory");
}
// GELU exact-erf via Abramowitz-Stegun 7.1.26 (|abs err| <= 1.5e-7)
__device__ inline float gelu_f(float x) {
  float ax = fabsf(x) * 0.70710678118654752f;
  float t = 1.f / (1.f + 0.3275911f * ax);
  float y = t * (0.254829592f + t * (-0.284496736f + t * (1.421413741f +
            t * (-1.453152027f + t * 1.061405429f))));
  float erfv = 1.f - y * __expf(-ax * ax);
  erfv = copysignf(erfv, x);
  return 0.5f * x * (1.f + erfv);
}

// ---------------- weight fp32 -> bf16 conversion ----------------
__global__ __launch_bounds__(256) void convert_k(
    const float* __restrict__ qw, const float* __restrict__ kw,
    const float* __restrict__ vw, const float* __restrict__ pw,
    const float* __restrict__ f1, const float* __restrict__ f2,
    __hip_bfloat16* __restrict__ out)
{
  int idx = blockIdx.x * 256 + threadIdx.x;
  if (idx >= 2 * 786432) return;
  int bi = idx / 786432;
  int r  = idx - bi * 786432;
  float v;
  if      (r <  65536) v = qw[bi*65536 + r];
  else if (r < 131072) v = kw[bi*65536 + r - 65536];
  else if (r < 196608) v = vw[bi*65536 + r - 131072];
  else if (r < 262144) v = pw[bi*65536 + r - 196608];
  else if (r < 524288) v = f1[bi*262144 + r - 262144];
  else                 v = f2[bi*262144 + r - 524288];
  out[idx] = __float2bfloat16(v);
}

// ---------------- fused prep: both LN1 variants + raw diff(bf16), BCHW -> (pix, ch) ----------------
__global__ __launch_bounds__(256) void prep2_k(
    const float* __restrict__ x,     // (2,4,256,64,64)
    const float* __restrict__ nw, const float* __restrict__ nb,
    __hip_bfloat16* __restrict__ ln1a,
    __hip_bfloat16* __restrict__ ln1b,
    __hip_bfloat16* __restrict__ diff,   // av*vi+ai*ir (raw, bf16)
    float av, float ai, float bv, float bb)
{
  __shared__ float t1[16][257], t2[16][257];
  __shared__ float red[4][16][16];
  __shared__ float mu1[16], rs1[16], mu2[16], rs2[16];
  int t = threadIdx.x;
  int pix0 = blockIdx.x * 16;
  int b = pix0 >> 12, hw0 = pix0 & 4095;
  const float* vi = x + (size_t)b * 256 * HWSZ;
  const float* ir = x + (size_t)(4 + b) * 256 * HWSZ;

  for (int it = 0; it < 16; ++it) {
    int idx = it * 256 + t;
    int p = idx & 15, c = idx >> 4;
    size_t off = (size_t)c * HWSZ + hw0 + p;
    float a = vi[off], bb2 = ir[off];
    t1[p][c] = av * a + ai * bb2;
    t2[p][c] = bv * a + bb * bb2;
  }
  __syncthreads();
  {
    int p = t & 15, q = t >> 4;
    float s1 = 0, ss1 = 0, s2 = 0, ss2 = 0;
    for (int i = 0; i < 16; ++i) {
      float v = t1[p][q*16 + i]; s1 += v; ss1 += v*v;
      float u = t2[p][q*16 + i]; s2 += u; ss2 += u*u;
    }
    red[0][p][q] = s1; red[1][p][q] = ss1; red[2][p][q] = s2; red[3][p][q] = ss2;
  }
  __syncthreads();
  if (t < 32) {
    int p = t & 15, which = t >> 4;
    float s = 0, ss = 0;
    for (int q = 0; q < 16; ++q) { s += red[which*2][p][q]; ss += red[which*2+1][p][q]; }
    float mu = s * (1.f/256.f);
    float var = ss * (1.f/256.f) - mu*mu;
    float rs = rsqrtf(var + 1e-5f);
    if (which == 0) { mu1[p] = mu; rs1[p] = rs; }
    else            { mu2[p] = mu; rs2[p] = rs; }
  }
  __syncthreads();
  for (int it = 0; it < 16; ++it) {
    float v1 = t1[it][t], v2 = t2[it][t];
    size_t o = (size_t)(pix0 + it) * 256 + t;
    ln1a[o] = __float2bfloat16((v1 - mu1[it]) * rs1[it] * nw[t] + nb[t]);
    ln1b[o] = __float2bfloat16((v2 - mu2[it]) * rs2[it] * nw[t] + nb[t]);
    diff[o] = __float2bfloat16(v1);
  }
}

// ---------------- 256-thread GEMM core (round-11 proven; used for proj) ----------------
template<int EPI, int BN>
__device__ __forceinline__ void gemm_core(
    const short* __restrict__ A, const short* __restrict__ W,
    void* __restrict__ outp, const float* __restrict__ bias,
    const short* __restrict__ res, int K, int ldc, int m0, int n0)
{
  constexpr int NI = (BN == 128) ? 4 : 2;
  __shared__ __align__(16) short As[2][64 * 32];
  __shared__ __align__(16) short Bs[2][BN * 32];
  int tid = threadIdx.x;
  int l = tid & 63, wv = tid >> 6;
  int wm = wv >> 1, wn = wv & 1;
  int lr = l & 15, lq = l >> 4;

  int srow = tid >> 2;
  int sch = (tid & 3) ^ ((srow >> 1) & 3);
  const short* gA = A + (size_t)(m0 + srow) * K + sch * 8;
  const short* gB = W + (size_t)(n0 + srow) * K + sch * 8;
  const short* gB1 = (BN == 128) ? (W + (size_t)(n0 + srow + 64) * K + sch * 8) : nullptr;

  f32x4 acc[2][NI];
  #pragma unroll
  for (int mi = 0; mi < 2; ++mi)
    #pragma unroll
    for (int ni = 0; ni < NI; ++ni) acc[mi][ni] = (f32x4){0.f, 0.f, 0.f, 0.f};

  gl16(gA, &As[0][0] + tid * 8);
  gl16(gB, &Bs[0][0] + tid * 8);
  if constexpr (BN == 128) gl16(gB1, &Bs[0][0] + 2048 + tid * 8);
  __syncthreads();

  int cur = 0;
  int rowa0 = wm * 32 + lr;
  int rowb0 = wn * (BN / 2) + lr;
  for (int k0 = 0; k0 < K; k0 += 32) {
    int kn = k0 + 32;
    if (kn < K) {
      gl16(gA + kn, &As[cur ^ 1][0] + tid * 8);
      gl16(gB + kn, &Bs[cur ^ 1][0] + tid * 8);
      if constexpr (BN == 128) gl16(gB1 + kn, &Bs[cur ^ 1][0] + 2048 + tid * 8);
    }
    bf16x8 af[2], bfr[NI];
    #pragma unroll
    for (int mi = 0; mi < 2; ++mi) {
      int row = rowa0 + mi * 16;
      int kc = lq ^ ((row >> 1) & 3);
      af[mi] = *(const bf16x8*)(&As[cur][0] + row * 32 + kc * 8);
    }
    #pragma unroll
    for (int ni = 0; ni < NI; ++ni) {
      int row = rowb0 + ni * 16;
      int kc = lq ^ ((row >> 1) & 3);
      bfr[ni] = *(const bf16x8*)(&Bs[cur][0] + row * 32 + kc * 8);
    }
    #pragma unroll
    for (int mi = 0; mi < 2; ++mi)
      #pragma unroll
      for (int ni = 0; ni < NI; ++ni)
        acc[mi][ni] = __builtin_amdgcn_mfma_f32_16x16x32_bf16(af[mi], bfr[ni], acc[mi][ni], 0, 0, 0);
    __syncthreads();
    cur ^= 1;
  }

  #pragma unroll
  for (int mi = 0; mi < 2; ++mi)
  #pragma unroll
  for (int ni = 0; ni < NI; ++ni) {
    int row0 = m0 + wm * 32 + mi * 16 + lq * 4;
    int col = n0 + wn * (BN / 2) + ni * 16 + lr;
    #pragma unroll
    for (int r = 0; r < 4; ++r) {
      int row = row0 + r;
      float v = acc[mi][ni][r];
      if (EPI == 0) {
        ((short*)outp)[(size_t)row * ldc + col] = f2b(v);
      } else {
        v += bias[col] + b2f(res[(size_t)row * 256 + col]);
        ((short*)outp)[(size_t)row * 256 + col] = f2b(v);
      }
    }
  }
}

template<int EPI, int BN>
__global__ __launch_bounds__(256) void gemm6_k(
    const short* __restrict__ A, const short* __restrict__ W,
    void* __restrict__ outp, const float* __restrict__ bias,
    const short* __restrict__ res, int K, int ldc)
{
  gemm_core<EPI, BN>(A, W, outp, bias, res, K, ldc, blockIdx.x * 64, blockIdx.y * BN);
}

// ---------------- 512-thread GEMM core: 128x128 tile, 8 waves (2m x 4n), wave 64x32 ----------------
// Proven (fc1 r16, qkv r18). Needs grid >= 3 blocks/CU to pay (round-17 lesson).
template<int EPI>
__device__ __forceinline__ void g512_core(
    const short* __restrict__ A, const short* __restrict__ W,
    void* __restrict__ outp, const float* __restrict__ bias,
    int K, int ldc, int m0, int n0)
{
  __shared__ __align__(16) short As[2][128 * 32];   // 8 KB each
  __shared__ __align__(16) short Bs[2][128 * 32];
  int tid = threadIdx.x;               // 0..511
  int l = tid & 63, wv = tid >> 6;     // 8 waves
  int wm = wv >> 2, wn = wv & 3;       // 2 x 4
  int lr = l & 15, lq = l >> 4;

  int srow = tid >> 2;
  int sch = (tid & 3) ^ ((srow >> 1) & 3);
  const short* gA = A + (size_t)(m0 + srow) * K + sch * 8;
  const short* gB = W + (size_t)(n0 + srow) * K + sch * 8;

  f32x4 acc[4][2];
  #pragma unroll
  for (int mi = 0; mi < 4; ++mi)
    #pragma unroll
    for (int ni = 0; ni < 2; ++ni) acc[mi][ni] = (f32x4){0.f, 0.f, 0.f, 0.f};

  gl16(gA, &As[0][0] + tid * 8);
  gl16(gB, &Bs[0][0] + tid * 8);
  __syncthreads();

  int cur = 0;
  int rowa0 = wm * 64 + lr;
  int rowb0 = wn * 32 + lr;
  for (int k0 = 0; k0 < K; k0 += 32) {
    int kn = k0 + 32;
    if (kn < K) {
      gl16(gA + kn, &As[cur ^ 1][0] + tid * 8);
      gl16(gB + kn, &Bs[cur ^ 1][0] + tid * 8);
    }
    bf16x8 af[4], bfr[2];
    #pragma unroll
    for (int mi = 0; mi < 4; ++mi) {
      int row = rowa0 + mi * 16;
      int kc = lq ^ ((row >> 1) & 3);
      af[mi] = *(const bf16x8*)(&As[cur][0] + row * 32 + kc * 8);
    }
    #pragma unroll
    for (int ni = 0; ni < 2; ++ni) {
      int row = rowb0 + ni * 16;
      int kc = lq ^ ((row >> 1) & 3);
      bfr[ni] = *(const bf16x8*)(&Bs[cur][0] + row * 32 + kc * 8);
    }
    #pragma unroll
    for (int mi = 0; mi < 4; ++mi)
      #pragma unroll
      for (int ni = 0; ni < 2; ++ni)
        acc[mi][ni] = __builtin_amdgcn_mfma_f32_16x16x32_bf16(af[mi], bfr[ni], acc[mi][ni], 0, 0, 0);
    __syncthreads();
    cur ^= 1;
  }

  #pragma unroll
  for (int mi = 0; mi < 4; ++mi)
  #pragma unroll
  for (int ni = 0; ni < 2; ++ni) {
    #pragma unroll
    for (int r = 0; r < 4; ++r) {
      int row = m0 + wm * 64 + mi * 16 + lq * 4 + r;
      int col = n0 + wn * 32 + ni * 16 + lr;
      float v = acc[mi][ni][r];
      if (EPI == 2) v = gelu_f(v + bias[col]);
      ((short*)outp)[(size_t)row * ldc + col] = f2b(v);
    }
  }
}

template<int EPI>
__global__ __launch_bounds__(512) void g512_k(
    const short* __restrict__ A, const short* __restrict__ W,
    void* __restrict__ outp, const float* __restrict__ bias,
    int K, int ldc)
{
  g512_core<EPI>(A, W, outp, bias, K, ldc, blockIdx.x * 128, blockIdx.y * 128);
}

// Q + KV in one 512-thread dispatch: y<2 -> Q (N=256), y>=2 -> KV (N=512); 768 blocks = 3/CU
__global__ __launch_bounds__(512) void qkv512_k(
    const short* __restrict__ ln1a, const short* __restrict__ ln1b,
    const short* __restrict__ wq, const short* __restrict__ wkv,
    short* __restrict__ qbuf, short* __restrict__ kv)
{
  bool isQ = blockIdx.y < 2;
  const short* A = isQ ? ln1a : ln1b;
  const short* W = isQ ? wq : wkv;
  void* outp = isQ ? (void*)qbuf : (void*)kv;
  int ldc = isQ ? 256 : 512;
  int n0 = (isQ ? blockIdx.y : (blockIdx.y - 2)) * 128;
  g512_core<0>(A, W, outp, nullptr, 256, ldc, blockIdx.x * 128, n0);
}

// ---------------- fc2 ring GEMM: counted-vmcnt, 4-buffer, 2-deep (K=1024, 32 steps) ----------------
__global__ __launch_bounds__(256) void gemm8_k(
    const short* __restrict__ A, const short* __restrict__ W,
    float* __restrict__ outp, const float* __restrict__ bias,
    const short* __restrict__ res, int K, int ldc)
{
  __shared__ __align__(16) short As[4][64 * 32];
  __shared__ __align__(16) short Bs[4][64 * 32];
  int tid = threadIdx.x;
  int l = tid & 63, wv = tid >> 6;
  int wm = wv >> 1, wn = wv & 1;
  int m0 = blockIdx.x * 64;
  int n0 = blockIdx.y * 64;
  int lr = l & 15, lq = l >> 4;

  int srow = tid >> 2;
  int sch = (tid & 3) ^ ((srow >> 1) & 3);
  const short* gA = A + (size_t)(m0 + srow) * K + sch * 8;
  const short* gB = W + (size_t)(n0 + srow) * K + sch * 8;

  f32x4 acc[2][2];
  #pragma unroll
  for (int mi = 0; mi < 2; ++mi)
    #pragma unroll
    for (int ni = 0; ni < 2; ++ni) acc[mi][ni] = (f32x4){0.f, 0.f, 0.f, 0.f};

  int T = K >> 5;
  #pragma unroll
  for (int t0 = 0; t0 < 2; ++t0) {
    gl16(gA + t0 * 32, &As[t0][0] + tid * 8);
    gl16(gB + t0 * 32, &Bs[t0][0] + tid * 8);
  }

  int rowa0 = wm * 32 + lr;
  int rowb0 = wn * 32 + lr;
  for (int t = 0; t < T; ++t) {
    if (t + 2 < T) {
      int b = (t + 2) & 3;
      gl16(gA + (t + 2) * 32, &As[b][0] + tid * 8);
      gl16(gB + (t + 2) * 32, &Bs[b][0] + tid * 8);
    }
    if (t < T - 2)       vmwait<4>();
    else if (t == T - 2) vmwait<2>();
    else                 vmwait<0>();
    __builtin_amdgcn_s_barrier();

    int cb = t & 3;
    bf16x8 af[2], bfr[2];
    #pragma unroll
    for (int mi = 0; mi < 2; ++mi) {
      int row = rowa0 + mi * 16;
      int kc = lq ^ ((row >> 1) & 3);
      af[mi] = *(const bf16x8*)(&As[cb][0] + row * 32 + kc * 8);
    }
    #pragma unroll
    for (int ni = 0; ni < 2; ++ni) {
      int row = rowb0 + ni * 16;
      int kc = lq ^ ((row >> 1) & 3);
      bfr[ni] = *(const bf16x8*)(&Bs[cb][0] + row * 32 + kc * 8);
    }
    #pragma unroll
    for (int mi = 0; mi < 2; ++mi)
      #pragma unroll
      for (int ni = 0; ni < 2; ++ni)
        acc[mi][ni] = __builtin_amdgcn_mfma_f32_16x16x32_bf16(af[mi], bfr[ni], acc[mi][ni], 0, 0, 0);
  }

  #pragma unroll
  for (int mi = 0; mi < 2; ++mi)
  #pragma unroll
  for (int ni = 0; ni < 2; ++ni) {
    int row0 = m0 + wm * 32 + mi * 16 + lq * 4;
    int col = n0 + wn * 32 + ni * 16 + lr;
    float bc = bias[col];
    float4 o;
    #pragma unroll
    for (int r = 0; r < 4; ++r)
      ((float*)&o)[r] = acc[mi][ni][r] + bc + b2f(res[(size_t)(row0 + r) * 256 + col]);
    int b = row0 >> 12, hw = row0 & 4095;
    *(float4*)(outp + (size_t)(b * 256 + col) * HWSZ + hw) = o;
  }
}

// ---------------- dilated local attention: one thread per (pixel, head) ----------------
__global__ __launch_bounds__(256) void attn2_k(
    const __hip_bfloat16* __restrict__ Q,
    const __hip_bfloat16* __restrict__ KV,
    __hip_bfloat16* __restrict__ out)
{
  int gid = blockIdx.x * 256 + threadIdx.x;
  int pix = gid >> 3, head = gid & 7;
  int dil = (head >> 1) + 1;
  int y = (pix >> 6) & 63, xc = pix & 63;
  int base = pix & ~4095;
  const short* q8 = (const short*)Q + (size_t)pix * 256 + head * 32;
  float qf[32];
  #pragma unroll
  for (int j = 0; j < 4; ++j) {
    bf16x8 v = *(const bf16x8*)(q8 + j * 8);
    #pragma unroll
    for (int e = 0; e < 8; ++e) qf[j*8 + e] = b2f(v[e]);
  }
  float lg[9];
  int npx[9];
  #pragma unroll
  for (int t = 0; t < 9; ++t) {
    int ny = y + (t / 3 - 1) * dil;
    int nx = xc + (t % 3 - 1) * dil;
    bool ok = ((unsigned)ny < 64u) && ((unsigned)nx < 64u);
    npx[t] = ok ? (base | (ny * 64 + nx)) : -1;
    float d = 0.f;
    if (ok) {
      const short* k8 = (const short*)KV + (size_t)npx[t] * 512 + head * 32;
      #pragma unroll
      for (int j = 0; j < 4; ++j) {
        bf16x8 v = *(const bf16x8*)(k8 + j * 8);
        #pragma unroll
        for (int e = 0; e < 8; ++e) d += qf[j*8 + e] * b2f(v[e]);
      }
    }
    lg[t] = d * 0.17677669529663687f;   // 32^-0.5
  }
  float m = lg[0];
  #pragma unroll
  for (int t = 1; t < 9; ++t) m = fmaxf(m, lg[t]);
  float w[9], den = 0.f;
  #pragma unroll
  for (int t = 0; t < 9; ++t) { w[t] = expf(lg[t] - m); den += w[t]; }
  float inv = 1.f / den;
  float acc[32];
  #pragma unroll
  for (int j = 0; j < 32; ++j) acc[j] = 0.f;
  #pragma unroll
  for (int t = 0; t < 9; ++t) {
    if (npx[t] >= 0) {
      const short* v8 = (const short*)KV + (size_t)npx[t] * 512 + 256 + head * 32;
      float wt = w[t];
      #pragma unroll
      for (int j = 0; j < 4; ++j) {
        bf16x8 v = *(const bf16x8*)(v8 + j * 8);
        #pragma unroll
        for (int e = 0; e < 8; ++e) acc[j*8 + e] += wt * b2f(v[e]);
      }
    }
  }
  short* op = (short*)out + (size_t)pix * 256 + head * 32;
  #pragma unroll
  for (int j = 0; j < 4; ++j) {
    bf16x8 o;
    #pragma unroll
    for (int e = 0; e < 8; ++e) o[e] = f2b(acc[j*8 + e] * inv);
    *(bf16x8*)(op + j * 8) = o;
  }
}

// ---------------- LN2: bf16 (pix,ch) -> bf16 (pix,ch) ----------------
__global__ __launch_bounds__(256) void ln2b_k(
    const __hip_bfloat16* __restrict__ xm, const float* __restrict__ w2,
    const float* __restrict__ b2, __hip_bfloat16* __restrict__ h)
{
  int pix = blockIdx.x * 4 + (threadIdx.x >> 6);
  int l = threadIdx.x & 63;
  const short* p = (const short*)xm + (size_t)pix * 256 + l * 4;
  short4 sv = *(const short4*)p;
  float vv[4] = {b2f(sv.x), b2f(sv.y), b2f(sv.z), b2f(sv.w)};
  float s = vv[0] + vv[1] + vv[2] + vv[3];
  float ss = vv[0]*vv[0] + vv[1]*vv[1] + vv[2]*vv[2] + vv[3]*vv[3];
  #pragma unroll
  for (int off = 32; off; off >>= 1) { s += __shfl_xor(s, off); ss += __shfl_xor(ss, off); }
  float mu = s * (1.f/256.f);
  float rstd = rsqrtf(ss * (1.f/256.f) - mu*mu + 1e-5f);
  #pragma unroll
  for (int j = 0; j < 4; ++j) {
    int c = l * 4 + j;
    h[(size_t)pix * 256 + c] = __float2bfloat16((vv[j] - mu) * rstd * w2[c] + b2[c]);
  }
}

extern "C" void kernel_launch(void* const* d_in, const int* in_sizes, int n_in,
                              void* d_out, int out_size, void* d_ws, size_t ws_size,
                              hipStream_t stream)
{
  const float* x   = (const float*)d_in[0];
  const float* n1w = (const float*)d_in[1];
  const float* n1b = (const float*)d_in[2];
  const float* qw  = (const float*)d_in[3];
  const float* kw  = (const float*)d_in[4];
  const float* vw  = (const float*)d_in[5];
  const float* pw  = (const float*)d_in[6];
  const float* pb  = (const float*)d_in[7];
  const float* n2w = (const float*)d_in[8];
  const float* n2b = (const float*)d_in[9];
  const float* f1w = (const float*)d_in[10];
  const float* f1b = (const float*)d_in[11];
  const float* f2w = (const float*)d_in[12];
  const float* f2b = (const float*)d_in[13];
  float* outp = (float*)d_out;
  char* ws = (char*)d_ws;

  const size_t MB = 1024 * 1024;
  // Workspace high-water 51 MB (proven safe):
  //   [0,3)   wbf (whole session)
  //   [3,11)  ln1a -> attnb -> h(low)
  //   [11,19) ln1b -> h
  //   [19,27) diff bf16 -> h
  //   [27,35) qbuf -> h(high)
  //   [3,35)  h 32MB (fc1 out; all above dead by then)
  //   [35,51) kv -> xmid bf16 [35,43) + hb [43,51)
  __hip_bfloat16* wbf   = (__hip_bfloat16*)(ws);
  __hip_bfloat16* ln1a  = (__hip_bfloat16*)(ws + 3*MB);
  __hip_bfloat16* attnb = (__hip_bfloat16*)(ws + 3*MB);
  __hip_bfloat16* h     = (__hip_bfloat16*)(ws + 3*MB);
  __hip_bfloat16* ln1b  = (__hip_bfloat16*)(ws + 11*MB);
  __hip_bfloat16* diff  = (__hip_bfloat16*)(ws + 19*MB);
  __hip_bfloat16* qbuf  = (__hip_bfloat16*)(ws + 27*MB);
  __hip_bfloat16* kv    = (__hip_bfloat16*)(ws + 35*MB);
  __hip_bfloat16* xmid  = (__hip_bfloat16*)(ws + 35*MB);
  __hip_bfloat16* hb    = (__hip_bfloat16*)(ws + 43*MB);

  convert_k<<<6144, 256, 0, stream>>>(qw, kw, vw, pw, f1w, f2w, wbf);

  for (int bi = 0; bi < 2; ++bi) {
    const short* wq  = (const short*)(wbf + (size_t)bi * 786432);
    const short* wkv = wq + 65536;           // kw rows then vw rows (512 x 256)
    const short* wp  = wq + 196608;
    const short* w1  = wq + 262144;
    const short* w2  = wq + 524288;
    float av = (bi == 0) ? 1.f : -1.f, ai = (bi == 0) ? -1.f : 1.f;
    float bv = (bi == 0) ? 0.f : 1.f,  bb = (bi == 0) ? 1.f : 0.f;

    prep2_k<<<1024, 256, 0, stream>>>(x, n1w + bi*256, n1b + bi*256, ln1a, ln1b, diff, av, ai, bv, bb);

    // Q (y 0-1) + KV (y 2-5) in one 512-thread dispatch, K=256 (768 blocks = 3/CU)
    qkv512_k<<<dim3(128, 6), 512, 0, stream>>>(
        (const short*)ln1a, (const short*)ln1b, wq, wkv, (short*)qbuf, (short*)kv);

    attn2_k<<<512, 256, 0, stream>>>(qbuf, kv, attnb);

    // proj: N=256, K=256, +bias +residual(diff) -> xmid bf16 (256-thr)
    gemm6_k<1, 64><<<dim3(256, 4), 256, 0, stream>>>(
        (const short*)attnb, wp, xmid, pb + bi*256, (const short*)diff, 256, 256);
    ln2b_k<<<4096, 256, 0, stream>>>(xmid, n2w + bi*256, n2b + bi*256, hb);

    // fc1: N=1024, K=256, gelu -> h (512-thr, proven)
    g512_k<2><<<dim3(128, 8), 512, 0, stream>>>(
        (const short*)hb, w1, (void*)h, f1b + bi*1024, 256, 1024);
    // fc2: N=256, K=1024 (32-step loop) -> ring-4 counted-vmcnt pipeline (4 blocks/CU)
    gemm8_k<<<dim3(256, 4), 256, 0, stream>>>(
        (const short*)h, w2, outp + (size_t)bi * 4194304, f2b + bi*256, (const short*)xmid, 1024, 256);
  }
}